// Round 1
// baseline (944.286 us; speedup 1.0000x reference)
//
#include <hip/hip_runtime.h>
#include <math.h>

#define B_      128
#define NNODES  2047   // 2*1024-1
#define NL_     64
#define DIN     512

// ---------------------------------------------------------------------------
// Kernel 1: E = exp(trans), elementwise 64x64.
// ---------------------------------------------------------------------------
__global__ __launch_bounds__(256) void kexp_trans(const float* __restrict__ trans,
                                                  float* __restrict__ E) {
    int i = blockIdx.x * 256 + threadIdx.x;
    if (i < NL_ * NL_) E[i] = __expf(trans[i]);
}

// ---------------------------------------------------------------------------
// Kernel 2: emis = hidden @ W + b   (fp32 tiled GEMM, M=262016, K=512, N=64)
// Block: 256 threads, tile 64 rows x 64 cols, K-chunks of 64.
// As padded to 68 floats/row: compute reads As[row][k] are broadcast/2-way
// (free per m136); Bs reads are per-k float4 (2-way, free).
// ---------------------------------------------------------------------------
__global__ __launch_bounds__(256) void kgemm(const float* __restrict__ H,
                                             const float* __restrict__ W,
                                             const float* __restrict__ bias,
                                             float* __restrict__ emis) {
    __shared__ float As[64][68];
    __shared__ float Bs[64][64];
    int t  = threadIdx.x;
    int rowBase = blockIdx.x * 64;
    int tx = t & 15;       // col group: cols tx*4 .. tx*4+3
    int ty = t >> 4;       // row group: rows ty*4 .. ty*4+3
    float acc[4][4] = {};

    for (int kc = 0; kc < DIN; kc += 64) {
        __syncthreads();
        #pragma unroll
        for (int p = 0; p < 4; ++p) {
            int f = t + p * 256;
            int r = f >> 4, q = f & 15;
            float4 av = *(const float4*)(H + (rowBase + r) * DIN + kc + q * 4);
            *(float4*)&As[r][q * 4] = av;
            float4 wv = *(const float4*)(W + (kc + r) * NL_ + q * 4);
            *(float4*)&Bs[r][q * 4] = wv;
        }
        __syncthreads();
        #pragma unroll
        for (int k = 0; k < 64; ++k) {
            float a0 = As[ty * 4 + 0][k];
            float a1 = As[ty * 4 + 1][k];
            float a2 = As[ty * 4 + 2][k];
            float a3 = As[ty * 4 + 3][k];
            float4 bv = *(const float4*)&Bs[k][tx * 4];
            acc[0][0] = fmaf(a0, bv.x, acc[0][0]); acc[0][1] = fmaf(a0, bv.y, acc[0][1]);
            acc[0][2] = fmaf(a0, bv.z, acc[0][2]); acc[0][3] = fmaf(a0, bv.w, acc[0][3]);
            acc[1][0] = fmaf(a1, bv.x, acc[1][0]); acc[1][1] = fmaf(a1, bv.y, acc[1][1]);
            acc[1][2] = fmaf(a1, bv.z, acc[1][2]); acc[1][3] = fmaf(a1, bv.w, acc[1][3]);
            acc[2][0] = fmaf(a2, bv.x, acc[2][0]); acc[2][1] = fmaf(a2, bv.y, acc[2][1]);
            acc[2][2] = fmaf(a2, bv.z, acc[2][2]); acc[2][3] = fmaf(a2, bv.w, acc[2][3]);
            acc[3][0] = fmaf(a3, bv.x, acc[3][0]); acc[3][1] = fmaf(a3, bv.y, acc[3][1]);
            acc[3][2] = fmaf(a3, bv.z, acc[3][2]); acc[3][3] = fmaf(a3, bv.w, acc[3][3]);
        }
    }
    float4 bv = *(const float4*)(bias + tx * 4);
    #pragma unroll
    for (int i = 0; i < 4; ++i) {
        float4 o;
        o.x = acc[i][0] + bv.x; o.y = acc[i][1] + bv.y;
        o.z = acc[i][2] + bv.z; o.w = acc[i][3] + bv.w;
        *(float4*)(emis + (rowBase + ty * 4 + i) * NL_ + tx * 4) = o;
    }
}

// ---------------------------------------------------------------------------
// Kernel 3: one tree level, lane-per-task. Level d has n=2^d nodes per batch,
// tasks = 128*2^d. Grid is fixed at 1024 waves (1 wave/SIMD); for smaller
// levels the j-loop is split J ways across waves (J = 1024/(tasks/64)).
// In-place: inside[g] = emis[g] + ml + log(E@el) + mr + log(E@er),
// children rows 2g+1, 2g+2 are CONTIGUOUS (128 floats) -> one vector stream.
// el/er live entirely in VGPRs (128 regs); E rows are wave-uniform loads.
// ---------------------------------------------------------------------------
__global__ __launch_bounds__(64) void klevel(float* __restrict__ inside,
                                             const float* __restrict__ E,
                                             int d) {
    int lane   = threadIdx.x;
    int n      = 1 << d;
    int groups = (B_ << d) >> 6;      // tasks / 64
    int J      = 1024 / groups;       // j-split factor
    int jw     = 64 / J;              // j's per wave
    int tg     = blockIdx.x / J;
    int j0     = (blockIdx.x % J) * jw;

    int task = tg * 64 + lane;
    int b    = task >> d;
    int i    = task & (n - 1);
    int g    = n - 1 + i;
    int rowL = (b * NNODES + 2 * g + 1) << 6;  // left child row; right = +64
    int rowG = (b * NNODES + g) << 6;

    float el[64], er[64];
    const float4* pC = (const float4*)(inside + rowL);
    #pragma unroll
    for (int q = 0; q < 16; ++q) {
        float4 v = pC[q];
        el[4*q] = v.x; el[4*q+1] = v.y; el[4*q+2] = v.z; el[4*q+3] = v.w;
    }
    #pragma unroll
    for (int q = 0; q < 16; ++q) {
        float4 v = pC[16 + q];
        er[4*q] = v.x; er[4*q+1] = v.y; er[4*q+2] = v.z; er[4*q+3] = v.w;
    }
    float ml = el[0], mr = er[0];
    #pragma unroll
    for (int k = 1; k < 64; ++k) { ml = fmaxf(ml, el[k]); mr = fmaxf(mr, er[k]); }
    #pragma unroll
    for (int k = 0; k < 64; ++k) {
        el[k] = __expf(el[k] - ml);
        er[k] = __expf(er[k] - mr);
    }
    float mbase = ml + mr;

    for (int jj = 0; jj < jw; ++jj) {
        int j = j0 + jj;
        const float4* Er = (const float4*)(E + (j << 6));   // wave-uniform
        float accl = 0.f, accr = 0.f;
        #pragma unroll
        for (int q = 0; q < 16; ++q) {
            float4 e = Er[q];
            accl = fmaf(el[4*q+0], e.x, accl); accl = fmaf(el[4*q+1], e.y, accl);
            accl = fmaf(el[4*q+2], e.z, accl); accl = fmaf(el[4*q+3], e.w, accl);
            accr = fmaf(er[4*q+0], e.x, accr); accr = fmaf(er[4*q+1], e.y, accr);
            accr = fmaf(er[4*q+2], e.z, accr); accr = fmaf(er[4*q+3], e.w, accr);
        }
        float ev = inside[rowG + j];
        inside[rowG + j] = ev + mbase + __logf(accl) + __logf(accr);
    }
}

// ---------------------------------------------------------------------------
// Kernel 4: fused tail, levels d=5..0. One block per batch (256 thr = 4
// waves), wave-per-task, j-parallel across lanes. E row j in lane j's
// registers (loaded once); el/er broadcast via v_readlane (VALU pipe — no
// DS-pipe contention). __syncthreads between levels (block == whole batch).
// Level 0 writes straight to d_out.
// ---------------------------------------------------------------------------
__global__ __launch_bounds__(256) void ktail(float* __restrict__ inside,
                                             const float* __restrict__ E,
                                             float* __restrict__ out) {
    int b    = blockIdx.x;
    int lane = threadIdx.x & 63;
    int wid  = threadIdx.x >> 6;

    float Ereg[64];
    const float4* E4 = (const float4*)(E + lane * NL_);
    #pragma unroll
    for (int q = 0; q < 16; ++q) {
        float4 v = E4[q];
        Ereg[4*q] = v.x; Ereg[4*q+1] = v.y; Ereg[4*q+2] = v.z; Ereg[4*q+3] = v.w;
    }
    int base = b * NNODES;

    for (int d = 5; d >= 0; --d) {
        int n = 1 << d;
        for (int i = wid; i < n; i += 4) {
            int g    = n - 1 + i;
            int rowC = (base + 2 * g + 1) << 6;
            float lf = inside[rowC + lane];
            float rf = inside[rowC + 64 + lane];
            float ml = lf, mr = rf;
            #pragma unroll
            for (int s = 32; s >= 1; s >>= 1) {
                ml = fmaxf(ml, __shfl_xor(ml, s));
                mr = fmaxf(mr, __shfl_xor(mr, s));
            }
            float el = __expf(lf - ml);
            float er = __expf(rf - mr);
            float accl = 0.f, accr = 0.f;
            #pragma unroll
            for (int k = 0; k < 64; ++k) {
                float ek = __int_as_float(__builtin_amdgcn_readlane(__float_as_int(el), k));
                float rk = __int_as_float(__builtin_amdgcn_readlane(__float_as_int(er), k));
                accl = fmaf(ek, Ereg[k], accl);
                accr = fmaf(rk, Ereg[k], accr);
            }
            int rowG  = (base + g) << 6;
            float res = inside[rowG + lane] + ml + mr + __logf(accl) + __logf(accr);
            if (d == 0) out[b * NL_ + lane] = res;
            else        inside[rowG + lane] = res;
        }
        __syncthreads();
    }
}

// ---------------------------------------------------------------------------
// Launch. ws layout: [E: 4096 floats][inside/emis: 128*2047*64 floats]
// total ~64 MiB. All launches on `stream`; no malloc/sync (graph-capture safe).
// ---------------------------------------------------------------------------
extern "C" void kernel_launch(void* const* d_in, const int* in_sizes, int n_in,
                              void* d_out, int out_size, void* d_ws, size_t ws_size,
                              hipStream_t stream) {
    const float* hidden = (const float*)d_in[0];
    const float* W      = (const float*)d_in[1];
    const float* bias   = (const float*)d_in[2];
    const float* trans  = (const float*)d_in[3];
    float* out    = (float*)d_out;
    float* E      = (float*)d_ws;
    float* inside = E + NL_ * NL_;

    kexp_trans<<<16, 256, 0, stream>>>(trans, E);
    kgemm<<<(B_ * NNODES) / 64, 256, 0, stream>>>(hidden, W, bias, inside);
    for (int d = 9; d >= 6; --d)
        klevel<<<1024, 64, 0, stream>>>(inside, E, d);
    ktail<<<B_, 256, 0, stream>>>(inside, E, out);
}

// Round 2
// 824.836 us; speedup vs baseline: 1.1448x; 1.1448x over previous
//
#include <hip/hip_runtime.h>
#include <math.h>

#define B_      128
#define NNODES  2047   // 2*1024-1
#define NL_     64
#define DIN     512

typedef __attribute__((ext_vector_type(8))) short short8;   // 8 bf16 (4 VGPRs)
typedef __attribute__((ext_vector_type(4))) float v4f;      // MFMA accumulator

// fp32 -> bf16 round-to-nearest-even
static __device__ inline unsigned short f2bf(float x) {
    unsigned u = __float_as_uint(x);
    u = (u + 0x7FFFu + ((u >> 16) & 1u)) >> 16;
    return (unsigned short)u;
}

// ---------------------------------------------------------------------------
// Kernel 1: E = exp(trans), elementwise 64x64.
// ---------------------------------------------------------------------------
__global__ __launch_bounds__(256) void kexp_trans(const float* __restrict__ trans,
                                                  float* __restrict__ E) {
    int i = blockIdx.x * 256 + threadIdx.x;
    if (i < NL_ * NL_) E[i] = __expf(trans[i]);
}

// ---------------------------------------------------------------------------
// Kernel 1b: Wt[n][k] = bf16(W[k][n])  (transpose + cast, 512x64 -> 64x512)
// ---------------------------------------------------------------------------
__global__ __launch_bounds__(256) void kprep(const float* __restrict__ W,
                                             unsigned short* __restrict__ Wt) {
    int i = blockIdx.x * 256 + threadIdx.x;   // 32768 elements
    int k = i >> 6, n = i & 63;
    Wt[n * DIN + k] = f2bf(W[i]);
}

// ---------------------------------------------------------------------------
// Kernel 2: emis = hidden @ W + b via bf16 MFMA (M=262016, K=512, N=64).
// Block 256 thr = 4 waves; 64-row x 64-col tile; K chunks of 64.
// LDS rows padded to 72 bf16 (144 B): frag b128 reads land 2-way/bank = free.
// Wave w owns rows w*16..w*16+15, all 64 cols (4 n-tiles), 16x16x32 MFMA.
// A frag: lane holds A[m=lane&15][k=quad*8+j]; B frag: B[n=lane&15][k=quad*8+j];
// D: col=lane&15, row=quad*4+reg (m89/m91-verified mapping).
// ---------------------------------------------------------------------------
__global__ __launch_bounds__(256) void kgemm(const float* __restrict__ H,
                                             const unsigned short* __restrict__ Wt,
                                             const float* __restrict__ bias,
                                             float* __restrict__ emis) {
    __shared__ unsigned short Al[64 * 72];
    __shared__ unsigned short Wl[64 * 72];
    int t = threadIdx.x;
    int rowBase = blockIdx.x * 64;
    int lane = t & 63;
    int w    = t >> 6;        // wave id -> row group
    int ln   = lane & 15;
    int quad = lane >> 4;

    v4f acc[4];
    #pragma unroll
    for (int i = 0; i < 4; ++i) acc[i] = (v4f){0.f, 0.f, 0.f, 0.f};

    int r   = t >> 2;         // staging row (A) / n (W)
    int sub = t & 3;
    const float* hrow = H + (long)(rowBase + r) * DIN + sub * 16;
    const unsigned short* wrow = Wt + r * DIN + sub * 8;

    for (int kc = 0; kc < DIN; kc += 64) {
        __syncthreads();
        // --- stage A: 64 rows x 64 k, fp32 -> bf16 ---
        #pragma unroll
        for (int i = 0; i < 4; ++i) {
            float4 v = *(const float4*)(hrow + kc + i * 4);
            unsigned long long pk =
                (unsigned long long)f2bf(v.x)
              | ((unsigned long long)f2bf(v.y) << 16)
              | ((unsigned long long)f2bf(v.z) << 32)
              | ((unsigned long long)f2bf(v.w) << 48);
            *(unsigned long long*)&Al[r * 72 + sub * 16 + i * 4] = pk;
        }
        // --- stage W: 64 n x 64 k bf16 copy ---
        #pragma unroll
        for (int i = 0; i < 2; ++i) {
            uint4 wv = *(const uint4*)(wrow + kc + i * 32);
            *(uint4*)&Wl[r * 72 + sub * 8 + i * 32] = wv;
        }
        __syncthreads();
        // --- MFMA: 2 k-sub of 32, 4 n-tiles ---
        const unsigned short* Ab = &Al[(w * 16 + ln) * 72];
        const unsigned short* Wb = &Wl[ln * 72];
        #pragma unroll
        for (int ks = 0; ks < 2; ++ks) {
            short8 af = *(const short8*)(Ab + ks * 32 + quad * 8);
            #pragma unroll
            for (int nt = 0; nt < 4; ++nt) {
                short8 bf = *(const short8*)(Wb + nt * 16 * 72 + ks * 32 + quad * 8);
                acc[nt] = __builtin_amdgcn_mfma_f32_16x16x32_bf16(af, bf, acc[nt], 0, 0, 0);
            }
        }
    }
    // --- epilogue: + bias, store fp32 ---
    #pragma unroll
    for (int nt = 0; nt < 4; ++nt) {
        float bv = bias[nt * 16 + ln];
        #pragma unroll
        for (int rg = 0; rg < 4; ++rg) {
            int row = rowBase + w * 16 + quad * 4 + rg;
            emis[(long)row * NL_ + nt * 16 + ln] = acc[nt][rg] + bv;
        }
    }
}

// ---------------------------------------------------------------------------
// Kernel 3: one tree level, lane-per-task, 2048 waves (2/SIMD).
// J = 2048/groups splits the j-loop across waves; parent-row RMW is float4.
// ---------------------------------------------------------------------------
__global__ __launch_bounds__(64, 2) void klevel(float* __restrict__ inside,
                                                const float* __restrict__ E,
                                                int d) {
    int lane   = threadIdx.x;
    int n      = 1 << d;
    int groups = (B_ << d) >> 6;      // tasks / 64
    int J      = 2048 / groups;       // j-split factor (d9:2 .. d6:16)
    int jw     = 64 / J;              // j's per wave (>=4)
    int tg     = blockIdx.x / J;
    int j0     = (blockIdx.x % J) * jw;

    int task = tg * 64 + lane;
    int b    = task >> d;
    int i    = task & (n - 1);
    int g    = n - 1 + i;
    int rowL = (b * NNODES + 2 * g + 1) << 6;  // left child row; right = +64
    int rowG = (b * NNODES + g) << 6;

    float el[64], er[64];
    const float4* pC = (const float4*)(inside + rowL);
    #pragma unroll
    for (int q = 0; q < 16; ++q) {
        float4 v = pC[q];
        el[4*q] = v.x; el[4*q+1] = v.y; el[4*q+2] = v.z; el[4*q+3] = v.w;
    }
    #pragma unroll
    for (int q = 0; q < 16; ++q) {
        float4 v = pC[16 + q];
        er[4*q] = v.x; er[4*q+1] = v.y; er[4*q+2] = v.z; er[4*q+3] = v.w;
    }
    float ml = el[0], mr = er[0];
    #pragma unroll
    for (int k = 1; k < 64; ++k) { ml = fmaxf(ml, el[k]); mr = fmaxf(mr, er[k]); }
    #pragma unroll
    for (int k = 0; k < 64; ++k) {
        el[k] = __expf(el[k] - ml);
        er[k] = __expf(er[k] - mr);
    }
    float mbase = ml + mr;

    for (int j4 = 0; j4 < jw; j4 += 4) {
        float res[4];
        #pragma unroll
        for (int jj = 0; jj < 4; ++jj) {
            const float4* Er = (const float4*)(E + ((j0 + j4 + jj) << 6)); // uniform
            float accl = 0.f, accr = 0.f;
            #pragma unroll
            for (int q = 0; q < 16; ++q) {
                float4 e = Er[q];
                accl = fmaf(el[4*q+0], e.x, accl); accl = fmaf(el[4*q+1], e.y, accl);
                accl = fmaf(el[4*q+2], e.z, accl); accl = fmaf(el[4*q+3], e.w, accl);
                accr = fmaf(er[4*q+0], e.x, accr); accr = fmaf(er[4*q+1], e.y, accr);
                accr = fmaf(er[4*q+2], e.z, accr); accr = fmaf(er[4*q+3], e.w, accr);
            }
            res[jj] = mbase + __logf(accl) + __logf(accr);
        }
        float4* pg = (float4*)(inside + rowG + j0 + j4);
        float4 ev = *pg;
        ev.x += res[0]; ev.y += res[1]; ev.z += res[2]; ev.w += res[3];
        *pg = ev;
    }
}

// ---------------------------------------------------------------------------
// Kernel 4: fused tail, levels d=5..0. One block per batch, wave-per-task,
// E row j in lane j's registers, readlane broadcast. Level 0 -> d_out.
// ---------------------------------------------------------------------------
__global__ __launch_bounds__(256) void ktail(float* __restrict__ inside,
                                             const float* __restrict__ E,
                                             float* __restrict__ out) {
    int b    = blockIdx.x;
    int lane = threadIdx.x & 63;
    int wid  = threadIdx.x >> 6;

    float Ereg[64];
    const float4* E4 = (const float4*)(E + lane * NL_);
    #pragma unroll
    for (int q = 0; q < 16; ++q) {
        float4 v = E4[q];
        Ereg[4*q] = v.x; Ereg[4*q+1] = v.y; Ereg[4*q+2] = v.z; Ereg[4*q+3] = v.w;
    }
    int base = b * NNODES;

    for (int d = 5; d >= 0; --d) {
        int n = 1 << d;
        for (int i = wid; i < n; i += 4) {
            int g    = n - 1 + i;
            int rowC = (base + 2 * g + 1) << 6;
            float lf = inside[rowC + lane];
            float rf = inside[rowC + 64 + lane];
            float ml = lf, mr = rf;
            #pragma unroll
            for (int s = 32; s >= 1; s >>= 1) {
                ml = fmaxf(ml, __shfl_xor(ml, s));
                mr = fmaxf(mr, __shfl_xor(mr, s));
            }
            float el = __expf(lf - ml);
            float er = __expf(rf - mr);
            float accl = 0.f, accr = 0.f;
            #pragma unroll
            for (int k = 0; k < 64; ++k) {
                float ek = __int_as_float(__builtin_amdgcn_readlane(__float_as_int(el), k));
                float rk = __int_as_float(__builtin_amdgcn_readlane(__float_as_int(er), k));
                accl = fmaf(ek, Ereg[k], accl);
                accr = fmaf(rk, Ereg[k], accr);
            }
            int rowG  = (base + g) << 6;
            float res = inside[rowG + lane] + ml + mr + __logf(accl) + __logf(accr);
            if (d == 0) out[b * NL_ + lane] = res;
            else        inside[rowG + lane] = res;
        }
        __syncthreads();
    }
}

// ---------------------------------------------------------------------------
// Launch. ws layout: [E: 4096 f][Wt bf16: 32768 us = 16384 f][inside: 16.7M f]
// ---------------------------------------------------------------------------
extern "C" void kernel_launch(void* const* d_in, const int* in_sizes, int n_in,
                              void* d_out, int out_size, void* d_ws, size_t ws_size,
                              hipStream_t stream) {
    const float* hidden = (const float*)d_in[0];
    const float* W      = (const float*)d_in[1];
    const float* bias   = (const float*)d_in[2];
    const float* trans  = (const float*)d_in[3];
    float* out = (float*)d_out;
    float* E   = (float*)d_ws;
    unsigned short* Wt = (unsigned short*)(E + NL_ * NL_);
    float* inside = E + NL_ * NL_ + (DIN * NL_ / 2);

    kexp_trans<<<16, 256, 0, stream>>>(trans, E);
    kprep<<<(DIN * NL_) / 256, 256, 0, stream>>>(W, Wt);
    kgemm<<<(B_ * NNODES) / 64, 256, 0, stream>>>(hidden, Wt, bias, inside);
    for (int d = 9; d >= 6; --d)
        klevel<<<2048, 64, 0, stream>>>(inside, E, d);
    ktail<<<B_, 256, 0, stream>>>(inside, E, out);
}